// Round 2
// baseline (600.106 us; speedup 1.0000x reference)
//
#include <hip/hip_runtime.h>

#define N_NODES 65536
#define N_EDGES 1048576
#define F_IN 64
#define F_OUT 128
#define KDIM (F_IN * 3)  // 192

// Fused init: T1 = 0, T2 = -X (vectorized float4)
__global__ __launch_bounds__(256) void init_t1_t2(const float* __restrict__ X,
                                                  float* __restrict__ T1,
                                                  float* __restrict__ T2)
{
    unsigned i = blockIdx.x * 256u + threadIdx.x;  // over float4s
    float4 x = ((const float4*)X)[i];
    float4 o;
    o.x = -x.x; o.y = -x.y; o.z = -x.z; o.w = -x.w;
    ((float4*)T2)[i] = o;
    ((float4*)T1)[i] = make_float4(0.f, 0.f, 0.f, 0.f);
}

// One wave (64 lanes) per edge: lane = feature index. row/col/val wave-uniform.
__global__ __launch_bounds__(256) void spmm_atomic(
    const int* __restrict__ erow, const int* __restrict__ ecol,
    const float* __restrict__ eval, const float* __restrict__ Y,
    float* __restrict__ out, float scale)
{
    unsigned long long tid = (unsigned long long)blockIdx.x * 256ull + threadIdx.x;
    unsigned e = (unsigned)(tid >> 6);
    unsigned f = (unsigned)(tid & 63u);
    if (e >= N_EDGES) return;
    int r = erow[e];
    int c = ecol[e];
    float v = scale * eval[e];
    atomicAdd(out + (size_t)r * F_IN + f, v * Y[(size_t)c * F_IN + f]);
}

// out[n, o] = sum_k H[n,k] * W[k,o] + b[o], H = [X | T1 | T2] (never materialized).
// Block: 256 threads, 32 rows x 128 cols tile. Thread: 4 rows x 4 cols.
__global__ __launch_bounds__(256) void gemm_out(
    const float* __restrict__ X, const float* __restrict__ T1,
    const float* __restrict__ T2, const float* __restrict__ W,
    const float* __restrict__ bias, float* __restrict__ out)
{
    __shared__ float Hs[32][KDIM];  // 32*192*4 = 24 KB
    int t = threadIdx.x;
    int brow = blockIdx.x * 32;

    // Stage 32 rows x 192 cols of H as float4 chunks (32*48 = 1536 chunks).
    for (int i = t; i < 32 * 48; i += 256) {
        int r = i / 48;
        int k4 = (i % 48) * 4;
        int gr = brow + r;
        const float* src;
        if (k4 < 64)       src = X  + (size_t)gr * F_IN + k4;
        else if (k4 < 128) src = T1 + (size_t)gr * F_IN + (k4 - 64);
        else               src = T2 + (size_t)gr * F_IN + (k4 - 128);
        *(float4*)&Hs[r][k4] = *(const float4*)src;
    }
    __syncthreads();

    int tc = t & 31;   // col group: cols tc*4 .. tc*4+3
    int tr = t >> 5;   // rows tr, tr+8, tr+16, tr+24
    float acc[4][4] = {};

    for (int k = 0; k < KDIM; ++k) {
        float4 w = *(const float4*)(W + (size_t)k * F_OUT + tc * 4);
        #pragma unroll
        for (int rr = 0; rr < 4; ++rr) {
            float h = Hs[tr + rr * 8][k];
            acc[rr][0] = fmaf(h, w.x, acc[rr][0]);
            acc[rr][1] = fmaf(h, w.y, acc[rr][1]);
            acc[rr][2] = fmaf(h, w.z, acc[rr][2]);
            acc[rr][3] = fmaf(h, w.w, acc[rr][3]);
        }
    }

    float4 bb = *(const float4*)(bias + tc * 4);
    #pragma unroll
    for (int rr = 0; rr < 4; ++rr) {
        int gr = brow + tr + rr * 8;
        float4 o;
        o.x = acc[rr][0] + bb.x;
        o.y = acc[rr][1] + bb.y;
        o.z = acc[rr][2] + bb.z;
        o.w = acc[rr][3] + bb.w;
        *(float4*)(out + (size_t)gr * F_OUT + tc * 4) = o;
    }
}

extern "C" void kernel_launch(void* const* d_in, const int* in_sizes, int n_in,
                              void* d_out, int out_size, void* d_ws, size_t ws_size,
                              hipStream_t stream)
{
    const float* X    = (const float*)d_in[0];
    const int*   erow = (const int*)  d_in[1];
    const int*   ecol = (const int*)  d_in[2];
    const float* eval = (const float*)d_in[3];
    const float* W    = (const float*)d_in[4];
    const float* bias = (const float*)d_in[5];
    float* out = (float*)d_out;

    float* T1 = (float*)d_ws;                       // 16 MB
    float* T2 = T1 + (size_t)N_NODES * F_IN;        // 16 MB

    // T1 = 0, T2 = -X (ws is poisoned 0xAA before every timed launch)
    init_t1_t2<<<(N_NODES * F_IN / 4) / 256, 256, 0, stream>>>(X, T1, T2);

    dim3 sgrid((N_EDGES * 64) / 256);  // one wave per edge, 4 edges/block
    // T1 += L @ X
    spmm_atomic<<<sgrid, 256, 0, stream>>>(erow, ecol, eval, X, T1, 1.0f);
    // T2 += 2 * L @ T1   (T2 pre-initialized to -X)
    spmm_atomic<<<sgrid, 256, 0, stream>>>(erow, ecol, eval, T1, T2, 2.0f);

    // out = [X|T1|T2] @ W + b
    gemm_out<<<N_NODES / 32, 256, 0, stream>>>(X, T1, T2, W, bias, out);
}

// Round 3
// 496.078 us; speedup vs baseline: 1.2097x; 1.2097x over previous
//
#include <hip/hip_runtime.h>

#define N_NODES 65536
#define N_EDGES 1048576
#define F_IN 64
#define F_OUT 128
#define KDIM (F_IN * 3)  // 192

// ---------------- CSR build (per call; ws/out are re-poisoned every run) ----

// zero the per-row counters (65536 ints) via int4 stores
__global__ __launch_bounds__(256) void zero_cur(int* __restrict__ cur)
{
    unsigned i = blockIdx.x * 256u + threadIdx.x;  // over int4s, 16384 total
    ((int4*)cur)[i] = make_int4(0, 0, 0, 0);
}

// histogram: count edges per row
__global__ __launch_bounds__(256) void hist(const int* __restrict__ erow,
                                            int* __restrict__ cur)
{
    unsigned e = blockIdx.x * 256u + threadIdx.x;
    atomicAdd(&cur[erow[e]], 1);
}

// single-block exclusive scan of 65536 counts -> off[0..65536]; cur <- off (cursors)
__global__ __launch_bounds__(1024) void scan_counts(int* __restrict__ cur,
                                                    int* __restrict__ off)
{
    __shared__ int s[1024];
    int t = threadIdx.x;
    int base = t * 64;
    int sum = 0;
    for (int i = 0; i < 64; ++i) sum += cur[base + i];
    s[t] = sum;
    __syncthreads();
    // Hillis-Steele inclusive scan over 1024 thread sums
    for (int d = 1; d < 1024; d <<= 1) {
        int v = (t >= d) ? s[t - d] : 0;
        __syncthreads();
        s[t] += v;
        __syncthreads();
    }
    int run = s[t] - sum;  // exclusive base for this thread
    for (int i = 0; i < 64; ++i) {
        int c = cur[base + i];
        off[base + i] = run;
        cur[base + i] = run;  // cursor for scatter
        run += c;
    }
    if (t == 1023) off[N_NODES] = run;  // == N_EDGES
}

// scatter edges into CSR order: csr[p] = {col, bitcast(val)}
__global__ __launch_bounds__(256) void scatter_edges(
    const int* __restrict__ erow, const int* __restrict__ ecol,
    const float* __restrict__ eval, int* __restrict__ cur,
    int2* __restrict__ csr)
{
    unsigned e = blockIdx.x * 256u + threadIdx.x;
    int r = erow[e];
    int p = atomicAdd(&cur[r], 1);
    csr[p] = make_int2(ecol[e], __float_as_int(eval[e]));
}

// ---------------- SpMM: one wave per row, register accumulation -------------
// MODE 1: out_row = sum(v * Y[c])            (T1 = L @ X)
// MODE 2: out_row = 2*sum(v * Y[c]) - X_row  (T2 = 2 L T1 - X)
template <int MODE>
__global__ __launch_bounds__(256) void spmm_csr(
    const int* __restrict__ off, const int2* __restrict__ csr,
    const float* __restrict__ Y, const float* __restrict__ X,
    float* __restrict__ out)
{
    int r    = blockIdx.x * 4 + (threadIdx.x >> 6);
    int lane = threadIdx.x & 63;
    int s = off[r];
    int e = off[r + 1];
    float acc = 0.f;
    for (int i = s; i < e; ++i) {
        int2 ed = csr[i];                       // wave-uniform broadcast load
        float v = __int_as_float(ed.y);
        acc = fmaf(v, Y[(size_t)ed.x * F_IN + lane], acc);
    }
    size_t o = (size_t)r * F_IN + lane;
    if (MODE == 1) out[o] = acc;
    else           out[o] = 2.f * acc - X[o];
}

// ---------------- fused concat-GEMM: out = [X|T1|T2] @ W + b ----------------
__global__ __launch_bounds__(256) void gemm_out(
    const float* __restrict__ X, const float* __restrict__ T1,
    const float* __restrict__ T2, const float* __restrict__ W,
    const float* __restrict__ bias, float* __restrict__ out)
{
    __shared__ float Hs[32][KDIM];  // 24 KB
    int t = threadIdx.x;
    int brow = blockIdx.x * 32;

    for (int i = t; i < 32 * 48; i += 256) {
        int r = i / 48;
        int k4 = (i % 48) * 4;
        int gr = brow + r;
        const float* src;
        if (k4 < 64)       src = X  + (size_t)gr * F_IN + k4;
        else if (k4 < 128) src = T1 + (size_t)gr * F_IN + (k4 - 64);
        else               src = T2 + (size_t)gr * F_IN + (k4 - 128);
        *(float4*)&Hs[r][k4] = *(const float4*)src;
    }
    __syncthreads();

    int tc = t & 31;   // cols tc*4 .. tc*4+3
    int tr = t >> 5;   // rows tr, tr+8, tr+16, tr+24
    float acc[4][4] = {};

    for (int k = 0; k < KDIM; ++k) {
        float4 w = *(const float4*)(W + (size_t)k * F_OUT + tc * 4);
        #pragma unroll
        for (int rr = 0; rr < 4; ++rr) {
            float h = Hs[tr + rr * 8][k];
            acc[rr][0] = fmaf(h, w.x, acc[rr][0]);
            acc[rr][1] = fmaf(h, w.y, acc[rr][1]);
            acc[rr][2] = fmaf(h, w.z, acc[rr][2]);
            acc[rr][3] = fmaf(h, w.w, acc[rr][3]);
        }
    }

    float4 bb = *(const float4*)(bias + tc * 4);
    #pragma unroll
    for (int rr = 0; rr < 4; ++rr) {
        int gr = brow + tr + rr * 8;
        float4 o;
        o.x = acc[rr][0] + bb.x;
        o.y = acc[rr][1] + bb.y;
        o.z = acc[rr][2] + bb.z;
        o.w = acc[rr][3] + bb.w;
        *(float4*)(out + (size_t)gr * F_OUT + tc * 4) = o;
    }
}

extern "C" void kernel_launch(void* const* d_in, const int* in_sizes, int n_in,
                              void* d_out, int out_size, void* d_ws, size_t ws_size,
                              hipStream_t stream)
{
    const float* X    = (const float*)d_in[0];
    const int*   erow = (const int*)  d_in[1];
    const int*   ecol = (const int*)  d_in[2];
    const float* eval = (const float*)d_in[3];
    const float* W    = (const float*)d_in[4];
    const float* bias = (const float*)d_in[5];
    float* out = (float*)d_out;

    // ws: T1 (16 MB) + T2 (16 MB)
    float* T1 = (float*)d_ws;
    float* T2 = T1 + (size_t)N_NODES * F_IN;

    // CSR scratch lives in d_out (8.9 MB < 33.5 MB). It is fully dead before
    // gemm_out overwrites d_out — stream ordering makes this safe.
    int*  off = (int*)d_out;          // 65537 ints (+ pad)
    int*  cur = off + 65600;          // 65536 ints
    int2* csr = (int2*)(cur + N_NODES); // 1M x 8 B

    zero_cur<<<64, 256, 0, stream>>>(cur);
    hist<<<N_EDGES / 256, 256, 0, stream>>>(erow, cur);
    scan_counts<<<1, 1024, 0, stream>>>(cur, off);
    scatter_edges<<<N_EDGES / 256, 256, 0, stream>>>(erow, ecol, eval, cur, csr);

    // T1 = L @ X ; T2 = 2 L T1 - X   (one wave per row, no atomics)
    spmm_csr<1><<<N_NODES / 4, 256, 0, stream>>>(off, csr, X, X, T1);
    spmm_csr<2><<<N_NODES / 4, 256, 0, stream>>>(off, csr, T1, X, T2);

    // out = [X|T1|T2] @ W + b
    gemm_out<<<N_NODES / 32, 256, 0, stream>>>(X, T1, T2, W, bias, out);
}

// Round 5
// 354.485 us; speedup vs baseline: 1.6929x; 1.3994x over previous
//
#include <hip/hip_runtime.h>

#define N_NODES 65536
#define N_EDGES 1048576
#define F_IN 64
#define F_OUT 128
#define KDIM (F_IN * 3)  // 192

// ---------------- CSR build ------------------------------------------------

__global__ __launch_bounds__(256) void zero_cur(int* __restrict__ cur)
{
    unsigned i = blockIdx.x * 256u + threadIdx.x;  // over int4s
    ((int4*)cur)[i] = make_int4(0, 0, 0, 0);
}

// histogram: 4 edges per thread
__global__ __launch_bounds__(256) void hist(const int* __restrict__ erow,
                                            int* __restrict__ cur)
{
    unsigned i = (blockIdx.x * 256u + threadIdx.x) * 4u;
    int4 r = *(const int4*)(erow + i);
    atomicAdd(&cur[r.x], 1);
    atomicAdd(&cur[r.y], 1);
    atomicAdd(&cur[r.z], 1);
    atomicAdd(&cur[r.w], 1);
}

// scan step 1: 64 blocks, each sums 1024 counts -> bsum[64]
__global__ __launch_bounds__(256) void scan_partial(const int* __restrict__ cur,
                                                    int* __restrict__ bsum)
{
    __shared__ int s[256];
    int t = threadIdx.x;
    int4 c = *(const int4*)(cur + blockIdx.x * 1024 + t * 4);
    s[t] = c.x + c.y + c.z + c.w;
    __syncthreads();
    for (int d = 128; d > 0; d >>= 1) {
        if (t < d) s[t] += s[t + d];
        __syncthreads();
    }
    if (t == 0) bsum[blockIdx.x] = s[0];
}

// scan step 2: exclusive scan of the 64 block sums (single wave)
__global__ __launch_bounds__(64) void scan_bsum(int* __restrict__ bsum)
{
    __shared__ int s[64];
    int t = threadIdx.x;
    int orig = bsum[t];
    s[t] = orig;
    __syncthreads();
    for (int d = 1; d < 64; d <<= 1) {
        int v = (t >= d) ? s[t - d] : 0;
        __syncthreads();
        s[t] += v;
        __syncthreads();
    }
    bsum[t] = s[t] - orig;
}

// scan step 3: local exclusive scan + block base -> off[], cur[] (cursors)
__global__ __launch_bounds__(256) void scan_final(int* __restrict__ cur,
                                                  const int* __restrict__ bsum,
                                                  int* __restrict__ off)
{
    __shared__ int s[256];
    int t = threadIdx.x;
    int base = blockIdx.x * 1024 + t * 4;
    int4 c = *(const int4*)(cur + base);
    int tsum = c.x + c.y + c.z + c.w;
    s[t] = tsum;
    __syncthreads();
    for (int d = 1; d < 256; d <<= 1) {
        int v = (t >= d) ? s[t - d] : 0;
        __syncthreads();
        s[t] += v;
        __syncthreads();
    }
    int tbase = bsum[blockIdx.x] + s[t] - tsum;  // exclusive base for this thread
    int4 o;
    o.x = tbase;
    o.y = o.x + c.x;
    o.z = o.y + c.y;
    o.w = o.z + c.z;
    *(int4*)(off + base) = o;
    *(int4*)(cur + base) = o;
    if (blockIdx.x == 63 && t == 255) off[N_NODES] = N_EDGES;
}

// scatter edges into CSR order: csr[p] = {col, bitcast(val)}
__global__ __launch_bounds__(256) void scatter_edges(
    const int* __restrict__ erow, const int* __restrict__ ecol,
    const float* __restrict__ eval, int* __restrict__ cur,
    int2* __restrict__ csr)
{
    unsigned e = blockIdx.x * 256u + threadIdx.x;
    int r = erow[e];
    int p = atomicAdd(&cur[r], 1);
    csr[p] = make_int2(ecol[e], __float_as_int(eval[e]));
}

// ---------------- SpMM: one wave per row, 4-way unrolled gathers ------------
// MODE 1: out_row = sum(v * Y[c])            (T1 = L @ X)
// MODE 2: out_row = 2*sum(v * Y[c]) - X_row  (T2 = 2 L T1 - X)
template <int MODE>
__global__ __launch_bounds__(256) void spmm_csr(
    const int* __restrict__ off, const int2* __restrict__ csr,
    const float* __restrict__ Y, const float* __restrict__ X,
    float* __restrict__ out)
{
    int r    = blockIdx.x * 4 + (threadIdx.x >> 6);
    int lane = threadIdx.x & 63;
    int s = off[r];
    int e = off[r + 1];
    float a0 = 0.f, a1 = 0.f, a2 = 0.f, a3 = 0.f;
    int i = s;
    for (; i + 4 <= e; i += 4) {
        int2 e0 = csr[i];
        int2 e1 = csr[i + 1];
        int2 e2 = csr[i + 2];
        int2 e3 = csr[i + 3];
        float y0 = Y[(size_t)e0.x * F_IN + lane];
        float y1 = Y[(size_t)e1.x * F_IN + lane];
        float y2 = Y[(size_t)e2.x * F_IN + lane];
        float y3 = Y[(size_t)e3.x * F_IN + lane];
        a0 = fmaf(__int_as_float(e0.y), y0, a0);
        a1 = fmaf(__int_as_float(e1.y), y1, a1);
        a2 = fmaf(__int_as_float(e2.y), y2, a2);
        a3 = fmaf(__int_as_float(e3.y), y3, a3);
    }
    for (; i < e; ++i) {
        int2 ed = csr[i];
        a0 = fmaf(__int_as_float(ed.y), Y[(size_t)ed.x * F_IN + lane], a0);
    }
    float acc = (a0 + a1) + (a2 + a3);
    size_t o = (size_t)r * F_IN + lane;
    if (MODE == 1) out[o] = acc;
    else           out[o] = 2.f * acc - X[o];
}

// ---------------- fused concat-GEMM: out = [X|T1|T2] @ W + b ----------------
__global__ __launch_bounds__(256) void gemm_out(
    const float* __restrict__ X, const float* __restrict__ T1,
    const float* __restrict__ T2, const float* __restrict__ W,
    const float* __restrict__ bias, float* __restrict__ out)
{
    __shared__ float Hs[32][KDIM];  // 24 KB
    int t = threadIdx.x;
    int brow = blockIdx.x * 32;

    for (int i = t; i < 32 * 48; i += 256) {
        int r = i / 48;
        int k4 = (i % 48) * 4;
        int gr = brow + r;
        const float* src;
        if (k4 < 64)       src = X  + (size_t)gr * F_IN + k4;
        else if (k4 < 128) src = T1 + (size_t)gr * F_IN + (k4 - 64);
        else               src = T2 + (size_t)gr * F_IN + (k4 - 128);
        *(float4*)&Hs[r][k4] = *(const float4*)src;
    }
    __syncthreads();

    int tc = t & 31;   // cols tc*4 .. tc*4+3
    int tr = t >> 5;   // rows tr, tr+8, tr+16, tr+24
    float acc[4][4] = {};

    for (int k4 = 0; k4 < KDIM; k4 += 4) {
        float4 w0 = *(const float4*)(W + (size_t)(k4 + 0) * F_OUT + tc * 4);
        float4 w1 = *(const float4*)(W + (size_t)(k4 + 1) * F_OUT + tc * 4);
        float4 w2 = *(const float4*)(W + (size_t)(k4 + 2) * F_OUT + tc * 4);
        float4 w3 = *(const float4*)(W + (size_t)(k4 + 3) * F_OUT + tc * 4);
        #pragma unroll
        for (int rr = 0; rr < 4; ++rr) {
            float4 h = *(const float4*)&Hs[tr + rr * 8][k4];
            acc[rr][0] = fmaf(h.x, w0.x, acc[rr][0]);
            acc[rr][1] = fmaf(h.x, w0.y, acc[rr][1]);
            acc[rr][2] = fmaf(h.x, w0.z, acc[rr][2]);
            acc[rr][3] = fmaf(h.x, w0.w, acc[rr][3]);
            acc[rr][0] = fmaf(h.y, w1.x, acc[rr][0]);
            acc[rr][1] = fmaf(h.y, w1.y, acc[rr][1]);
            acc[rr][2] = fmaf(h.y, w1.z, acc[rr][2]);
            acc[rr][3] = fmaf(h.y, w1.w, acc[rr][3]);
            acc[rr][0] = fmaf(h.z, w2.x, acc[rr][0]);
            acc[rr][1] = fmaf(h.z, w2.y, acc[rr][1]);
            acc[rr][2] = fmaf(h.z, w2.z, acc[rr][2]);
            acc[rr][3] = fmaf(h.z, w2.w, acc[rr][3]);
            acc[rr][0] = fmaf(h.w, w3.x, acc[rr][0]);
            acc[rr][1] = fmaf(h.w, w3.y, acc[rr][1]);
            acc[rr][2] = fmaf(h.w, w3.z, acc[rr][2]);
            acc[rr][3] = fmaf(h.w, w3.w, acc[rr][3]);
        }
    }

    float4 bb = *(const float4*)(bias + tc * 4);
    #pragma unroll
    for (int rr = 0; rr < 4; ++rr) {
        int gr = brow + tr + rr * 8;
        float4 o;
        o.x = acc[rr][0] + bb.x;
        o.y = acc[rr][1] + bb.y;
        o.z = acc[rr][2] + bb.z;
        o.w = acc[rr][3] + bb.w;
        *(float4*)(out + (size_t)gr * F_OUT + tc * 4) = o;
    }
}

extern "C" void kernel_launch(void* const* d_in, const int* in_sizes, int n_in,
                              void* d_out, int out_size, void* d_ws, size_t ws_size,
                              hipStream_t stream)
{
    const float* X    = (const float*)d_in[0];
    const int*   erow = (const int*)  d_in[1];
    const int*   ecol = (const int*)  d_in[2];
    const float* eval = (const float*)d_in[3];
    const float* W    = (const float*)d_in[4];
    const float* bias = (const float*)d_in[5];
    float* out = (float*)d_out;

    // ws: T1 (16 MB) + T2 (16 MB)
    float* T1 = (float*)d_ws;
    float* T2 = T1 + (size_t)N_NODES * F_IN;

    // CSR scratch in d_out (~8.9 MB < 33.5 MB); dead before gemm_out writes.
    int*  off  = (int*)d_out;            // 65537 ints (+ pad to 65600)
    int*  cur  = off + 65600;            // 65536 ints
    int2* csr  = (int2*)(cur + N_NODES); // 1M x 8 B
    int*  bsum = (int*)(csr + N_EDGES);  // 64 ints

    zero_cur<<<64, 256, 0, stream>>>(cur);
    hist<<<N_EDGES / 1024, 256, 0, stream>>>(erow, cur);
    scan_partial<<<64, 256, 0, stream>>>(cur, bsum);
    scan_bsum<<<1, 64, 0, stream>>>(bsum);
    scan_final<<<64, 256, 0, stream>>>(cur, bsum, off);
    scatter_edges<<<N_EDGES / 256, 256, 0, stream>>>(erow, ecol, eval, cur, csr);

    // T1 = L @ X ; T2 = 2 L T1 - X   (one wave per row, no atomics)
    spmm_csr<1><<<N_NODES / 4, 256, 0, stream>>>(off, csr, X, X, T1);
    spmm_csr<2><<<N_NODES / 4, 256, 0, stream>>>(off, csr, T1, X, T2);

    // out = [X|T1|T2] @ W + b
    gemm_out<<<N_NODES / 32, 256, 0, stream>>>(X, T1, T2, W, bias, out);
}

// Round 7
// 266.951 us; speedup vs baseline: 2.2480x; 1.3279x over previous
//
#include <hip/hip_runtime.h>

#define N_NODES 65536
#define N_EDGES 1048576
#define F_IN 64
#define F_OUT 128
#define KDIM (F_IN * 3)  // 192
#define NB 1024          // row buckets (64 rows each): bucket = row >> 6

// ---------------- bucketed CSR build ---------------------------------------
// d_out scratch layout (ints):
//   off  [0      .. 65536]   (pad to 65600)
//   csr  [65600  .. +2M]     int2 {col, val}
//   boff [2162752.. +1025]   (pad to 1088)
//   bcur [2163840.. +1024]
//   bent [2164864.. +2M]     int2 {(row<<16)|col, val}
// total ~17 MB < 33.5 MB out buffer; all dead before gemm_out writes out.

__global__ __launch_bounds__(256) void zero_bcur(int* __restrict__ bcur)
{
    ((int4*)bcur)[threadIdx.x] = make_int4(0, 0, 0, 0);  // 256 int4 = 1024 ints
}

// LDS-aggregated bucket histogram: 128 blocks x 8192 edges
__global__ __launch_bounds__(256) void bucket_hist(const int* __restrict__ erow,
                                                   int* __restrict__ bcur)
{
    __shared__ int h[NB];
    int t = threadIdx.x;
    for (int i = t; i < NB; i += 256) h[i] = 0;
    __syncthreads();
    int base = blockIdx.x * 8192;
    for (int j = 0; j < 8; ++j) {
        int4 r = *(const int4*)(erow + base + j * 1024 + t * 4);
        atomicAdd(&h[r.x >> 6], 1);
        atomicAdd(&h[r.y >> 6], 1);
        atomicAdd(&h[r.z >> 6], 1);
        atomicAdd(&h[r.w >> 6], 1);
    }
    __syncthreads();
    for (int i = t; i < NB; i += 256)
        if (h[i]) atomicAdd(&bcur[i], h[i]);
}

// exclusive scan of 1024 bucket counts -> boff[0..1024]; bcur <- bases (cursors)
__global__ __launch_bounds__(256) void scan_buckets(int* __restrict__ bcur,
                                                    int* __restrict__ boff)
{
    __shared__ int s[256];
    int t = threadIdx.x;
    int4 c = ((const int4*)bcur)[t];
    int tsum = c.x + c.y + c.z + c.w;
    s[t] = tsum;
    __syncthreads();
    for (int d = 1; d < 256; d <<= 1) {
        int v = (t >= d) ? s[t - d] : 0;
        __syncthreads();
        s[t] += v;
        __syncthreads();
    }
    int run = s[t] - tsum;  // exclusive base
    int4 o;
    o.x = run;
    o.y = o.x + c.x;
    o.z = o.y + c.y;
    o.w = o.z + c.z;
    ((int4*)boff)[t] = o;
    ((int4*)bcur)[t] = o;
    if (t == 255) boff[NB] = N_EDGES;
}

// pass 1: scatter edges into bucket-grouped bent[] with per-(block,bucket) runs
__global__ __launch_bounds__(256) void bucketize(
    const int* __restrict__ erow, const int* __restrict__ ecol,
    const float* __restrict__ eval, int* __restrict__ bcur,
    const int* __restrict__ boff_unused, int2* __restrict__ bent)
{
    __shared__ int h[NB];      // count, then local cursor
    __shared__ int gbase[NB];  // global base for this block's run
    int t = threadIdx.x;
    for (int i = t; i < NB; i += 256) h[i] = 0;
    __syncthreads();
    int base = blockIdx.x * 8192;
    for (int j = 0; j < 8; ++j) {
        int4 r = *(const int4*)(erow + base + j * 1024 + t * 4);
        atomicAdd(&h[r.x >> 6], 1);
        atomicAdd(&h[r.y >> 6], 1);
        atomicAdd(&h[r.z >> 6], 1);
        atomicAdd(&h[r.w >> 6], 1);
    }
    __syncthreads();
    for (int i = t; i < NB; i += 256) {
        int cnt = h[i];
        gbase[i] = cnt ? atomicAdd(&bcur[i], cnt) : 0;
        h[i] = 0;  // reuse as local cursor
    }
    __syncthreads();
    for (int j = 0; j < 8; ++j) {
        int4   r = *(const int4*)(erow + base + j * 1024 + t * 4);
        int4   c = *(const int4*)(ecol + base + j * 1024 + t * 4);
        float4 v = *(const float4*)(eval + base + j * 1024 + t * 4);
        {
            int b = r.x >> 6; int p = atomicAdd(&h[b], 1);
            bent[gbase[b] + p] = make_int2((int)(((unsigned)r.x << 16) | (unsigned)c.x), __float_as_int(v.x));
        }
        {
            int b = r.y >> 6; int p = atomicAdd(&h[b], 1);
            bent[gbase[b] + p] = make_int2((int)(((unsigned)r.y << 16) | (unsigned)c.y), __float_as_int(v.y));
        }
        {
            int b = r.z >> 6; int p = atomicAdd(&h[b], 1);
            bent[gbase[b] + p] = make_int2((int)(((unsigned)r.z << 16) | (unsigned)c.z), __float_as_int(v.z));
        }
        {
            int b = r.w >> 6; int p = atomicAdd(&h[b], 1);
            bent[gbase[b] + p] = make_int2((int)(((unsigned)r.w << 16) | (unsigned)c.w), __float_as_int(v.w));
        }
    }
}

// pass 2: one block per bucket. Builds off[] for its 64 rows and scatters its
// entries into the bucket's contiguous CSR range (single-CU write window ->
// full-line assembly in local L2).
__global__ __launch_bounds__(256) void build_csr(
    const int* __restrict__ boff, const int2* __restrict__ bent,
    int* __restrict__ off, int2* __restrict__ csr)
{
    __shared__ int rh[64];     // row hist, then row cursor
    __shared__ int rbase[64];  // csr base per row
    int b = blockIdx.x;
    int t = threadIdx.x;
    int s = boff[b];
    int e = boff[b + 1];
    int n = e - s;
    if (t < 64) rh[t] = 0;
    __syncthreads();
    for (int i = t; i < n; i += 256) {
        unsigned rc = (unsigned)bent[s + i].x;
        atomicAdd(&rh[(rc >> 16) & 63], 1);
    }
    __syncthreads();
    if (t == 0) {
        int run = s;
        for (int k = 0; k < 64; ++k) { rbase[k] = run; run += rh[k]; }
    }
    __syncthreads();
    if (t < 64) {
        off[b * 64 + t] = rbase[t];
        rh[t] = 0;  // reuse as cursor
    }
    if (b == NB - 1 && t == 0) off[N_NODES] = N_EDGES;
    __syncthreads();
    for (int i = t; i < n; i += 256) {
        int2 en = bent[s + i];
        unsigned rc = (unsigned)en.x;
        int rl = (rc >> 16) & 63;
        int p = atomicAdd(&rh[rl], 1);
        csr[rbase[rl] + p] = make_int2((int)(rc & 0xFFFFu), en.y);
    }
}

// ---------------- SpMM: one wave per row, 4-way unrolled gathers ------------
// MODE 1: out_row = sum(v * Y[c])            (T1 = L @ X)
// MODE 2: out_row = 2*sum(v * Y[c]) - X_row  (T2 = 2 L T1 - X)
template <int MODE>
__global__ __launch_bounds__(256) void spmm_csr(
    const int* __restrict__ off, const int2* __restrict__ csr,
    const float* __restrict__ Y, const float* __restrict__ X,
    float* __restrict__ out)
{
    int r    = blockIdx.x * 4 + (threadIdx.x >> 6);
    int lane = threadIdx.x & 63;
    int s = off[r];
    int e = off[r + 1];
    float a0 = 0.f, a1 = 0.f, a2 = 0.f, a3 = 0.f;
    int i = s;
    for (; i + 4 <= e; i += 4) {
        int2 e0 = csr[i];
        int2 e1 = csr[i + 1];
        int2 e2 = csr[i + 2];
        int2 e3 = csr[i + 3];
        float y0 = Y[(size_t)e0.x * F_IN + lane];
        float y1 = Y[(size_t)e1.x * F_IN + lane];
        float y2 = Y[(size_t)e2.x * F_IN + lane];
        float y3 = Y[(size_t)e3.x * F_IN + lane];
        a0 = fmaf(__int_as_float(e0.y), y0, a0);
        a1 = fmaf(__int_as_float(e1.y), y1, a1);
        a2 = fmaf(__int_as_float(e2.y), y2, a2);
        a3 = fmaf(__int_as_float(e3.y), y3, a3);
    }
    for (; i < e; ++i) {
        int2 ed = csr[i];
        a0 = fmaf(__int_as_float(ed.y), Y[(size_t)ed.x * F_IN + lane], a0);
    }
    float acc = (a0 + a1) + (a2 + a3);
    size_t o = (size_t)r * F_IN + lane;
    if (MODE == 1) out[o] = acc;
    else           out[o] = 2.f * acc - X[o];
}

// ---------------- fused concat-GEMM: out = [X|T1|T2] @ W + b ----------------
__global__ __launch_bounds__(256) void gemm_out(
    const float* __restrict__ X, const float* __restrict__ T1,
    const float* __restrict__ T2, const float* __restrict__ W,
    const float* __restrict__ bias, float* __restrict__ out)
{
    __shared__ float Hs[32][KDIM];  // 24 KB
    int t = threadIdx.x;
    int brow = blockIdx.x * 32;

    for (int i = t; i < 32 * 48; i += 256) {
        int r = i / 48;
        int k4 = (i % 48) * 4;
        int gr = brow + r;
        const float* src;
        if (k4 < 64)       src = X  + (size_t)gr * F_IN + k4;
        else if (k4 < 128) src = T1 + (size_t)gr * F_IN + (k4 - 64);
        else               src = T2 + (size_t)gr * F_IN + (k4 - 128);
        *(float4*)&Hs[r][k4] = *(const float4*)src;
    }
    __syncthreads();

    int tc = t & 31;   // cols tc*4 .. tc*4+3
    int tr = t >> 5;   // rows tr, tr+8, tr+16, tr+24
    float acc[4][4] = {};

    for (int k4 = 0; k4 < KDIM; k4 += 4) {
        float4 w0 = *(const float4*)(W + (size_t)(k4 + 0) * F_OUT + tc * 4);
        float4 w1 = *(const float4*)(W + (size_t)(k4 + 1) * F_OUT + tc * 4);
        float4 w2 = *(const float4*)(W + (size_t)(k4 + 2) * F_OUT + tc * 4);
        float4 w3 = *(const float4*)(W + (size_t)(k4 + 3) * F_OUT + tc * 4);
        #pragma unroll
        for (int rr = 0; rr < 4; ++rr) {
            float4 h = *(const float4*)&Hs[tr + rr * 8][k4];
            acc[rr][0] = fmaf(h.x, w0.x, acc[rr][0]);
            acc[rr][1] = fmaf(h.x, w0.y, acc[rr][1]);
            acc[rr][2] = fmaf(h.x, w0.z, acc[rr][2]);
            acc[rr][3] = fmaf(h.x, w0.w, acc[rr][3]);
            acc[rr][0] = fmaf(h.y, w1.x, acc[rr][0]);
            acc[rr][1] = fmaf(h.y, w1.y, acc[rr][1]);
            acc[rr][2] = fmaf(h.y, w1.z, acc[rr][2]);
            acc[rr][3] = fmaf(h.y, w1.w, acc[rr][3]);
            acc[rr][0] = fmaf(h.z, w2.x, acc[rr][0]);
            acc[rr][1] = fmaf(h.z, w2.y, acc[rr][1]);
            acc[rr][2] = fmaf(h.z, w2.z, acc[rr][2]);
            acc[rr][3] = fmaf(h.z, w2.w, acc[rr][3]);
            acc[rr][0] = fmaf(h.w, w3.x, acc[rr][0]);
            acc[rr][1] = fmaf(h.w, w3.y, acc[rr][1]);
            acc[rr][2] = fmaf(h.w, w3.z, acc[rr][2]);
            acc[rr][3] = fmaf(h.w, w3.w, acc[rr][3]);
        }
    }

    float4 bb = *(const float4*)(bias + tc * 4);
    #pragma unroll
    for (int rr = 0; rr < 4; ++rr) {
        int gr = brow + tr + rr * 8;
        float4 o;
        o.x = acc[rr][0] + bb.x;
        o.y = acc[rr][1] + bb.y;
        o.z = acc[rr][2] + bb.z;
        o.w = acc[rr][3] + bb.w;
        *(float4*)(out + (size_t)gr * F_OUT + tc * 4) = o;
    }
}

extern "C" void kernel_launch(void* const* d_in, const int* in_sizes, int n_in,
                              void* d_out, int out_size, void* d_ws, size_t ws_size,
                              hipStream_t stream)
{
    const float* X    = (const float*)d_in[0];
    const int*   erow = (const int*)  d_in[1];
    const int*   ecol = (const int*)  d_in[2];
    const float* eval = (const float*)d_in[3];
    const float* W    = (const float*)d_in[4];
    const float* bias = (const float*)d_in[5];
    float* out = (float*)d_out;

    // ws: T1 (16 MB) + T2 (16 MB)
    float* T1 = (float*)d_ws;
    float* T2 = T1 + (size_t)N_NODES * F_IN;

    // CSR scratch in d_out (~17 MB < 33.5 MB); all dead before gemm_out writes.
    int*  off  = (int*)d_out;                 // 65537 (pad 65600)
    int2* csr  = (int2*)(off + 65600);        // 1M x 8 B
    int*  boff = (int*)(csr + N_EDGES);       // 1025 (pad 1088)
    int*  bcur = boff + 1088;                 // 1024
    int2* bent = (int2*)(bcur + 1024);        // 1M x 8 B

    zero_bcur<<<1, 256, 0, stream>>>(bcur);
    bucket_hist<<<128, 256, 0, stream>>>(erow, bcur);
    scan_buckets<<<1, 256, 0, stream>>>(bcur, boff);
    bucketize<<<128, 256, 0, stream>>>(erow, ecol, eval, bcur, boff, bent);
    build_csr<<<NB, 256, 0, stream>>>(boff, bent, off, csr);

    // T1 = L @ X ; T2 = 2 L T1 - X   (one wave per row, no atomics)
    spmm_csr<1><<<N_NODES / 4, 256, 0, stream>>>(off, csr, X, X, T1);
    spmm_csr<2><<<N_NODES / 4, 256, 0, stream>>>(off, csr, T1, X, T2);

    // out = [X|T1|T2] @ W + b
    gemm_out<<<N_NODES / 32, 256, 0, stream>>>(X, T1, T2, W, bias, out);
}

// Round 11
// 218.218 us; speedup vs baseline: 2.7500x; 1.2233x over previous
//
#include <hip/hip_runtime.h>

#define N_NODES 65536
#define N_EDGES 1048576
#define F_IN 64
#define F_OUT 128
#define KDIM (F_IN * 3)  // 192
#define NB 1024          // row buckets (64 rows each): bucket = row >> 6

typedef float f32x4 __attribute__((ext_vector_type(4)));
typedef short bf16x8 __attribute__((ext_vector_type(8)));

// round-to-nearest-even f32 -> bf16 (inputs are finite normals)
static __device__ __forceinline__ unsigned short f2bf(float f)
{
    unsigned u = __float_as_uint(f);
    u += 0x7FFFu + ((u >> 16) & 1u);
    return (unsigned short)(u >> 16);
}
static __device__ __forceinline__ float bf2f(unsigned short h)
{
    return __uint_as_float((unsigned)h << 16);
}

// ---------------- bf16 conversions ------------------------------------------

// Wp packed+swizzled bf16 for B-fragments of mfma_f32_16x16x32_bf16:
// element W[kk*32 + g*8 + j][n*16 + c15] stored at
//   p = (((kk*8 + n)*16 + c15)*4 + (g ^ (c15&3)))*8 + j
__global__ __launch_bounds__(256) void wpack(const float* __restrict__ W,
                                             unsigned short* __restrict__ Wp)
{
    int p = blockIdx.x * 256 + threadIdx.x;   // 24576 total
    int j   = p & 7;
    int gx  = (p >> 3) & 3;
    int c15 = (p >> 5) & 15;
    int n   = (p >> 9) & 7;
    int kk  = p >> 12;
    int g   = gx ^ (c15 & 3);
    int k   = kk * 32 + g * 8 + j;
    int c   = n * 16 + c15;
    Wp[p] = f2bf(W[k * F_OUT + c]);
}

__global__ __launch_bounds__(256) void xconvert(const float* __restrict__ X,
                                                unsigned short* __restrict__ Xb)
{
    unsigned i = (blockIdx.x * 256u + threadIdx.x) * 4u;
    float4 x = *(const float4*)(X + i);
    ushort4 o;
    o.x = f2bf(x.x); o.y = f2bf(x.y); o.z = f2bf(x.z); o.w = f2bf(x.w);
    *(ushort4*)(Xb + i) = o;
}

// ---------------- bucketed CSR build ----------------------------------------

__global__ __launch_bounds__(256) void zero_bcur(int* __restrict__ bcur)
{
    ((int4*)bcur)[threadIdx.x] = make_int4(0, 0, 0, 0);
}

__global__ __launch_bounds__(256) void bucket_hist(const int* __restrict__ erow,
                                                   int* __restrict__ bcur)
{
    __shared__ int h[NB];
    int t = threadIdx.x;
    for (int i = t; i < NB; i += 256) h[i] = 0;
    __syncthreads();
    int base = blockIdx.x * 8192;
    for (int j = 0; j < 8; ++j) {
        int4 r = *(const int4*)(erow + base + j * 1024 + t * 4);
        atomicAdd(&h[r.x >> 6], 1);
        atomicAdd(&h[r.y >> 6], 1);
        atomicAdd(&h[r.z >> 6], 1);
        atomicAdd(&h[r.w >> 6], 1);
    }
    __syncthreads();
    for (int i = t; i < NB; i += 256)
        if (h[i]) atomicAdd(&bcur[i], h[i]);
}

__global__ __launch_bounds__(256) void scan_buckets(int* __restrict__ bcur,
                                                    int* __restrict__ boff)
{
    __shared__ int s[256];
    int t = threadIdx.x;
    int4 c = ((const int4*)bcur)[t];
    int tsum = c.x + c.y + c.z + c.w;
    s[t] = tsum;
    __syncthreads();
    for (int d = 1; d < 256; d <<= 1) {
        int v = (t >= d) ? s[t - d] : 0;
        __syncthreads();
        s[t] += v;
        __syncthreads();
    }
    int run = s[t] - tsum;
    int4 o;
    o.x = run;
    o.y = o.x + c.x;
    o.z = o.y + c.y;
    o.w = o.z + c.z;
    ((int4*)boff)[t] = o;
    ((int4*)bcur)[t] = o;
    if (t == 255) boff[NB] = N_EDGES;
}

__global__ __launch_bounds__(256) void bucketize(
    const int* __restrict__ erow, const int* __restrict__ ecol,
    const float* __restrict__ eval, int* __restrict__ bcur,
    int2* __restrict__ bent)
{
    __shared__ int h[NB];
    __shared__ int gbase[NB];
    int t = threadIdx.x;
    for (int i = t; i < NB; i += 256) h[i] = 0;
    __syncthreads();
    int base = blockIdx.x * 8192;
    for (int j = 0; j < 8; ++j) {
        int4 r = *(const int4*)(erow + base + j * 1024 + t * 4);
        atomicAdd(&h[r.x >> 6], 1);
        atomicAdd(&h[r.y >> 6], 1);
        atomicAdd(&h[r.z >> 6], 1);
        atomicAdd(&h[r.w >> 6], 1);
    }
    __syncthreads();
    for (int i = t; i < NB; i += 256) {
        int cnt = h[i];
        gbase[i] = cnt ? atomicAdd(&bcur[i], cnt) : 0;
        h[i] = 0;
    }
    __syncthreads();
    for (int j = 0; j < 8; ++j) {
        int4   r = *(const int4*)(erow + base + j * 1024 + t * 4);
        int4   c = *(const int4*)(ecol + base + j * 1024 + t * 4);
        float4 v = *(const float4*)(eval + base + j * 1024 + t * 4);
        {
            int b = r.x >> 6; int p = atomicAdd(&h[b], 1);
            bent[gbase[b] + p] = make_int2((int)(((unsigned)r.x << 16) | (unsigned)c.x), __float_as_int(v.x));
        }
        {
            int b = r.y >> 6; int p = atomicAdd(&h[b], 1);
            bent[gbase[b] + p] = make_int2((int)(((unsigned)r.y << 16) | (unsigned)c.y), __float_as_int(v.y));
        }
        {
            int b = r.z >> 6; int p = atomicAdd(&h[b], 1);
            bent[gbase[b] + p] = make_int2((int)(((unsigned)r.z << 16) | (unsigned)c.z), __float_as_int(v.z));
        }
        {
            int b = r.w >> 6; int p = atomicAdd(&h[b], 1);
            bent[gbase[b] + p] = make_int2((int)(((unsigned)r.w << 16) | (unsigned)c.w), __float_as_int(v.w));
        }
    }
}

__global__ __launch_bounds__(256) void build_csr(
    const int* __restrict__ boff, const int2* __restrict__ bent,
    int* __restrict__ off, int2* __restrict__ csr)
{
    __shared__ int rh[64];
    __shared__ int rbase[64];
    int b = blockIdx.x;
    int t = threadIdx.x;
    int s = boff[b];
    int e = boff[b + 1];
    int n = e - s;
    if (t < 64) rh[t] = 0;
    __syncthreads();
    for (int i = t; i < n; i += 256) {
        unsigned rc = (unsigned)bent[s + i].x;
        atomicAdd(&rh[(rc >> 16) & 63], 1);
    }
    __syncthreads();
    if (t == 0) {
        int run = s;
        for (int k = 0; k < 64; ++k) { rbase[k] = run; run += rh[k]; }
    }
    __syncthreads();
    if (t < 64) {
        off[b * 64 + t] = rbase[t];
        rh[t] = 0;
    }
    if (b == NB - 1 && t == 0) off[N_NODES] = N_EDGES;
    __syncthreads();
    for (int i = t; i < n; i += 256) {
        int2 en = bent[s + i];
        unsigned rc = (unsigned)en.x;
        int rl = (rc >> 16) & 63;
        int p = atomicAdd(&rh[rl], 1);
        csr[rbase[rl] + p] = make_int2((int)(rc & 0xFFFFu), en.y);
    }
}

// ---------------- SpMM: bf16 gathers, f32 accumulate, bf16 out --------------
// MODE 1: T1b = bf16( sum v * Yb[c] )
// MODE 2: T2b = bf16( 2*sum(v * Yb[c]) - X[row] )
template <int MODE>
__global__ __launch_bounds__(256) void spmm_b(
    const int* __restrict__ off, const int2* __restrict__ csr,
    const unsigned short* __restrict__ Yb, const float* __restrict__ X,
    unsigned short* __restrict__ outb)
{
    int r    = blockIdx.x * 4 + (threadIdx.x >> 6);
    int lane = threadIdx.x & 63;
    int s = off[r];
    int e = off[r + 1];
    float a0 = 0.f, a1 = 0.f, a2 = 0.f, a3 = 0.f;
    int i = s;
    for (; i + 4 <= e; i += 4) {
        int2 e0 = csr[i];
        int2 e1 = csr[i + 1];
        int2 e2 = csr[i + 2];
        int2 e3 = csr[i + 3];
        float y0 = bf2f(Yb[(size_t)e0.x * F_IN + lane]);
        float y1 = bf2f(Yb[(size_t)e1.x * F_IN + lane]);
        float y2 = bf2f(Yb[(size_t)e2.x * F_IN + lane]);
        float y3 = bf2f(Yb[(size_t)e3.x * F_IN + lane]);
        a0 = fmaf(__int_as_float(e0.y), y0, a0);
        a1 = fmaf(__int_as_float(e1.y), y1, a1);
        a2 = fmaf(__int_as_float(e2.y), y2, a2);
        a3 = fmaf(__int_as_float(e3.y), y3, a3);
    }
    for (; i < e; ++i) {
        int2 ed = csr[i];
        a0 = fmaf(__int_as_float(ed.y), bf2f(Yb[(size_t)ed.x * F_IN + lane]), a0);
    }
    float acc = (a0 + a1) + (a2 + a3);
    size_t o = (size_t)r * F_IN + lane;
    if (MODE == 2) acc = 2.f * acc - X[o];
    outb[o] = f2bf(acc);
}

// ---------------- MFMA GEMM: out = [Xb|T1b|T2b] @ W + b ---------------------
// 512 threads = 8 waves; block tile 128 rows x 128 cols; wave = 16 rows.
// A-frags direct from global (each element read once); B from LDS (packed Wp).
__global__ __launch_bounds__(512) void gemm_mfma(
    const unsigned short* __restrict__ Xb, const unsigned short* __restrict__ T1b,
    const unsigned short* __restrict__ T2b, const unsigned short* __restrict__ Wp,
    const float* __restrict__ bias, float* __restrict__ out)
{
    __shared__ __align__(16) unsigned short Wl[24576];  // 48 KB
    int t = threadIdx.x;
    // stage packed W: 24576 ushorts = 3072 float4 chunks
    for (int i = t; i < 3072; i += 512)
        ((float4*)Wl)[i] = ((const float4*)Wp)[i];
    __syncthreads();

    int w   = t >> 6;
    int l   = t & 63;
    int c15 = l & 15;
    int g   = l >> 4;
    int brow = blockIdx.x * 128 + w * 16;
    int arow = brow + c15;

    const unsigned short* srcs[3] = {Xb, T1b, T2b};
    bf16x8 a[6];
    #pragma unroll
    for (int kk = 0; kk < 6; ++kk) {
        const unsigned short* src = srcs[kk >> 1];
        a[kk] = *(const bf16x8*)(src + (size_t)arow * F_IN + (kk & 1) * 32 + g * 8);
    }

    f32x4 acc[8];
    #pragma unroll
    for (int n = 0; n < 8; ++n) acc[n] = (f32x4){0.f, 0.f, 0.f, 0.f};

    int gx = g ^ (c15 & 3);
    #pragma unroll
    for (int kk = 0; kk < 6; ++kk) {
        #pragma unroll
        for (int n = 0; n < 8; ++n) {
            int idx = (((kk * 8 + n) * 16 + c15) * 4 + gx) * 8;
            bf16x8 b = *(const bf16x8*)&Wl[idx];
            acc[n] = __builtin_amdgcn_mfma_f32_16x16x32_bf16(a[kk], b, acc[n], 0, 0, 0);
        }
    }

    #pragma unroll
    for (int n = 0; n < 8; ++n) {
        float bv = bias[n * 16 + c15];
        #pragma unroll
        for (int r = 0; r < 4; ++r) {
            int orow = brow + g * 4 + r;
            out[(size_t)orow * F_OUT + n * 16 + c15] = acc[n][r] + bv;
        }
    }
}

extern "C" void kernel_launch(void* const* d_in, const int* in_sizes, int n_in,
                              void* d_out, int out_size, void* d_ws, size_t ws_size,
                              hipStream_t stream)
{
    const float* X    = (const float*)d_in[0];
    const int*   erow = (const int*)  d_in[1];
    const int*   ecol = (const int*)  d_in[2];
    const float* eval = (const float*)d_in[3];
    const float* W    = (const float*)d_in[4];
    const float* bias = (const float*)d_in[5];
    float* out = (float*)d_out;

    // ws layout: Xb (8MB) + T1b (8MB) + T2b (8MB) + Wp (48KB) < 32MB
    unsigned short* Xb  = (unsigned short*)d_ws;
    unsigned short* T1b = Xb  + (size_t)N_NODES * F_IN;
    unsigned short* T2b = T1b + (size_t)N_NODES * F_IN;
    unsigned short* Wp  = T2b + (size_t)N_NODES * F_IN;

    // CSR scratch in d_out (~17 MB < 33.5 MB); all dead before gemm writes out.
    int*  off  = (int*)d_out;                 // 65537 (pad 65600)
    int2* csr  = (int2*)(off + 65600);        // 1M x 8 B
    int*  boff = (int*)(csr + N_EDGES);       // 1025 (pad 1088)
    int*  bcur = boff + 1088;                 // 1024
    int2* bent = (int2*)(bcur + 1024);        // 1M x 8 B

    wpack<<<96, 256, 0, stream>>>(W, Wp);
    xconvert<<<N_NODES * F_IN / 4 / 256, 256, 0, stream>>>(X, Xb);

    zero_bcur<<<1, 256, 0, stream>>>(bcur);
    bucket_hist<<<128, 256, 0, stream>>>(erow, bcur);
    scan_buckets<<<1, 256, 0, stream>>>(bcur, boff);
    bucketize<<<128, 256, 0, stream>>>(erow, ecol, eval, bcur, bent);
    build_csr<<<NB, 256, 0, stream>>>(boff, bent, off, csr);

    // T1b = bf16(L @ Xb) ; T2b = bf16(2 L T1b - X)
    spmm_b<1><<<N_NODES / 4, 256, 0, stream>>>(off, csr, Xb, X, T1b);
    spmm_b<2><<<N_NODES / 4, 256, 0, stream>>>(off, csr, T1b, X, T2b);

    // out = [Xb|T1b|T2b] @ W + b   (bf16 MFMA, f32 accumulate)
    gemm_mfma<<<N_NODES / 128, 512, 0, stream>>>(Xb, T1b, T2b, Wp, bias, out);
}

// Round 13
// 214.857 us; speedup vs baseline: 2.7931x; 1.0156x over previous
//
#include <hip/hip_runtime.h>

#define N_NODES 65536
#define N_EDGES 1048576
#define F_IN 64
#define F_OUT 128
#define NB 1024          // row buckets (64 rows each): bucket = row >> 6
#define ENT_CAP 1536     // max edges per bucket (Poisson(1024), 16 sigma margin)

typedef float f32x4 __attribute__((ext_vector_type(4)));
typedef short bf16x8 __attribute__((ext_vector_type(8)));

static __device__ __forceinline__ unsigned short f2bf(float f)
{
    unsigned u = __float_as_uint(f);
    u += 0x7FFFu + ((u >> 16) & 1u);
    return (unsigned short)(u >> 16);
}
static __device__ __forceinline__ float bf2f(unsigned short h)
{
    return __uint_as_float((unsigned)h << 16);
}

// ---------------- bf16 conversions ------------------------------------------

// Wp packed+swizzled bf16 for B-fragments of mfma_f32_16x16x32_bf16:
// element W[kk*32 + g*8 + j][n*16 + c15] stored at
//   p = (((kk*8 + n)*16 + c15)*4 + (g ^ (c15&3)))*8 + j
__global__ __launch_bounds__(256) void wpack(const float* __restrict__ W,
                                             unsigned short* __restrict__ Wp)
{
    int p = blockIdx.x * 256 + threadIdx.x;   // 24576 total
    int j   = p & 7;
    int gx  = (p >> 3) & 3;
    int c15 = (p >> 5) & 15;
    int n   = (p >> 9) & 7;
    int kk  = p >> 12;
    int g   = gx ^ (c15 & 3);
    int k   = kk * 32 + g * 8 + j;
    int c   = n * 16 + c15;
    Wp[p] = f2bf(W[k * F_OUT + c]);
}

__global__ __launch_bounds__(256) void xconvert(const float* __restrict__ X,
                                                unsigned short* __restrict__ Xb)
{
    unsigned i = (blockIdx.x * 256u + threadIdx.x) * 4u;
    float4 x = *(const float4*)(X + i);
    ushort4 o;
    o.x = f2bf(x.x); o.y = f2bf(x.y); o.z = f2bf(x.z); o.w = f2bf(x.w);
    *(ushort4*)(Xb + i) = o;
}

// ---------------- bucketed edge grouping ------------------------------------

__global__ __launch_bounds__(256) void zero_bcur(int* __restrict__ bcur)
{
    ((int4*)bcur)[threadIdx.x] = make_int4(0, 0, 0, 0);
}

__global__ __launch_bounds__(256) void bucket_hist(const int* __restrict__ erow,
                                                   int* __restrict__ bcur)
{
    __shared__ int h[NB];
    int t = threadIdx.x;
    for (int i = t; i < NB; i += 256) h[i] = 0;
    __syncthreads();
    int base = blockIdx.x * 8192;
    for (int j = 0; j < 8; ++j) {
        int4 r = *(const int4*)(erow + base + j * 1024 + t * 4);
        atomicAdd(&h[r.x >> 6], 1);
        atomicAdd(&h[r.y >> 6], 1);
        atomicAdd(&h[r.z >> 6], 1);
        atomicAdd(&h[r.w >> 6], 1);
    }
    __syncthreads();
    for (int i = t; i < NB; i += 256)
        if (h[i]) atomicAdd(&bcur[i], h[i]);
}

__global__ __launch_bounds__(256) void scan_buckets(int* __restrict__ bcur,
                                                    int* __restrict__ boff)
{
    __shared__ int s[256];
    int t = threadIdx.x;
    int4 c = ((const int4*)bcur)[t];
    int tsum = c.x + c.y + c.z + c.w;
    s[t] = tsum;
    __syncthreads();
    for (int d = 1; d < 256; d <<= 1) {
        int v = (t >= d) ? s[t - d] : 0;
        __syncthreads();
        s[t] += v;
        __syncthreads();
    }
    int run = s[t] - tsum;
    int4 o;
    o.x = run;
    o.y = o.x + c.x;
    o.z = o.y + c.y;
    o.w = o.z + c.z;
    ((int4*)boff)[t] = o;
    ((int4*)bcur)[t] = o;
    if (t == 255) boff[NB] = N_EDGES;
}

__global__ __launch_bounds__(256) void bucketize(
    const int* __restrict__ erow, const int* __restrict__ ecol,
    const float* __restrict__ eval, int* __restrict__ bcur,
    int2* __restrict__ bent)
{
    __shared__ int h[NB];
    __shared__ int gbase[NB];
    int t = threadIdx.x;
    for (int i = t; i < NB; i += 256) h[i] = 0;
    __syncthreads();
    int base = blockIdx.x * 8192;
    for (int j = 0; j < 8; ++j) {
        int4 r = *(const int4*)(erow + base + j * 1024 + t * 4);
        atomicAdd(&h[r.x >> 6], 1);
        atomicAdd(&h[r.y >> 6], 1);
        atomicAdd(&h[r.z >> 6], 1);
        atomicAdd(&h[r.w >> 6], 1);
    }
    __syncthreads();
    for (int i = t; i < NB; i += 256) {
        int cnt = h[i];
        gbase[i] = cnt ? atomicAdd(&bcur[i], cnt) : 0;
        h[i] = 0;
    }
    __syncthreads();
    for (int j = 0; j < 8; ++j) {
        int4   r = *(const int4*)(erow + base + j * 1024 + t * 4);
        int4   c = *(const int4*)(ecol + base + j * 1024 + t * 4);
        float4 v = *(const float4*)(eval + base + j * 1024 + t * 4);
        {
            int b = r.x >> 6; int p = atomicAdd(&h[b], 1);
            bent[gbase[b] + p] = make_int2((int)(((unsigned)r.x << 16) | (unsigned)c.x), __float_as_int(v.x));
        }
        {
            int b = r.y >> 6; int p = atomicAdd(&h[b], 1);
            bent[gbase[b] + p] = make_int2((int)(((unsigned)r.y << 16) | (unsigned)c.y), __float_as_int(v.y));
        }
        {
            int b = r.z >> 6; int p = atomicAdd(&h[b], 1);
            bent[gbase[b] + p] = make_int2((int)(((unsigned)r.z << 16) | (unsigned)c.z), __float_as_int(v.z));
        }
        {
            int b = r.w >> 6; int p = atomicAdd(&h[b], 1);
            bent[gbase[b] + p] = make_int2((int)(((unsigned)r.w << 16) | (unsigned)c.w), __float_as_int(v.w));
        }
    }
}

// ---------------- fused: build CSR window + spmm-1 (T1b = bf16(L @ Xb)) -----
// One block per bucket (64 rows). Builds off[]/csr[] for spmm-2, keeps sorted
// entries in LDS, then 4 waves compute T1 rows straight from LDS.
__global__ __launch_bounds__(256) void build_spmm1(
    const int* __restrict__ boff, const int2* __restrict__ bent,
    int* __restrict__ off, int2* __restrict__ csr,
    const unsigned short* __restrict__ Xb, unsigned short* __restrict__ T1b)
{
    __shared__ int rh[64];       // row hist -> cursor -> count
    __shared__ int rbase[64];    // local row base within bucket
    __shared__ int2 ent[ENT_CAP];
    int b = blockIdx.x;
    int t = threadIdx.x;
    int s = boff[b];
    int e = boff[b + 1];
    int n = e - s;
    if (t < 64) rh[t] = 0;
    __syncthreads();
    for (int i = t; i < n; i += 256)
        atomicAdd(&rh[((unsigned)bent[s + i].x >> 16) & 63], 1);
    __syncthreads();
    if (t == 0) {
        int run = 0;
        for (int k = 0; k < 64; ++k) { rbase[k] = run; run += rh[k]; }
    }
    __syncthreads();
    if (t < 64) {
        off[b * 64 + t] = s + rbase[t];
        rh[t] = 0;  // reuse as cursor
    }
    if (b == NB - 1 && t == 0) off[N_NODES] = N_EDGES;
    __syncthreads();
    for (int i = t; i < n; i += 256) {
        int2 en = bent[s + i];
        unsigned rc = (unsigned)en.x;
        int rl = (rc >> 16) & 63;
        int p = rbase[rl] + atomicAdd(&rh[rl], 1);
        int2 cv = make_int2((int)(rc & 0xFFFFu), en.y);
        ent[p] = cv;
        csr[s + p] = cv;     // contiguous window write for spmm-2
    }
    __syncthreads();
    // spmm phase: wave wv handles rows wv*16 .. wv*16+15 of this bucket
    int wv   = t >> 6;
    int lane = t & 63;
    for (int rr = 0; rr < 16; ++rr) {
        int rl = wv * 16 + rr;
        int ls = rbase[rl];
        int le = ls + rh[rl];
        float a0 = 0.f, a1 = 0.f, a2 = 0.f, a3 = 0.f;
        float a4 = 0.f, a5 = 0.f, a6 = 0.f, a7 = 0.f;
        int i = ls;
        for (; i + 8 <= le; i += 8) {
            int2 e0 = ent[i];     int2 e1 = ent[i + 1];
            int2 e2 = ent[i + 2]; int2 e3 = ent[i + 3];
            int2 e4 = ent[i + 4]; int2 e5 = ent[i + 5];
            int2 e6 = ent[i + 6]; int2 e7 = ent[i + 7];
            float y0 = bf2f(Xb[(size_t)e0.x * F_IN + lane]);
            float y1 = bf2f(Xb[(size_t)e1.x * F_IN + lane]);
            float y2 = bf2f(Xb[(size_t)e2.x * F_IN + lane]);
            float y3 = bf2f(Xb[(size_t)e3.x * F_IN + lane]);
            float y4 = bf2f(Xb[(size_t)e4.x * F_IN + lane]);
            float y5 = bf2f(Xb[(size_t)e5.x * F_IN + lane]);
            float y6 = bf2f(Xb[(size_t)e6.x * F_IN + lane]);
            float y7 = bf2f(Xb[(size_t)e7.x * F_IN + lane]);
            a0 = fmaf(__int_as_float(e0.y), y0, a0);
            a1 = fmaf(__int_as_float(e1.y), y1, a1);
            a2 = fmaf(__int_as_float(e2.y), y2, a2);
            a3 = fmaf(__int_as_float(e3.y), y3, a3);
            a4 = fmaf(__int_as_float(e4.y), y4, a4);
            a5 = fmaf(__int_as_float(e5.y), y5, a5);
            a6 = fmaf(__int_as_float(e6.y), y6, a6);
            a7 = fmaf(__int_as_float(e7.y), y7, a7);
        }
        for (; i < le; ++i) {
            int2 ed = ent[i];
            a0 = fmaf(__int_as_float(ed.y), bf2f(Xb[(size_t)ed.x * F_IN + lane]), a0);
        }
        float acc = ((a0 + a1) + (a2 + a3)) + ((a4 + a5) + (a6 + a7));
        int r = b * 64 + rl;
        T1b[(size_t)r * F_IN + lane] = f2bf(acc);
    }
}

// ---------------- SpMM-2: T2b = bf16(2*(L @ T1b) - X), 8-way unrolled -------
__global__ __launch_bounds__(256) void spmm2(
    const int* __restrict__ off, const int2* __restrict__ csr,
    const unsigned short* __restrict__ Yb, const float* __restrict__ X,
    unsigned short* __restrict__ outb)
{
    int r    = blockIdx.x * 4 + (threadIdx.x >> 6);
    int lane = threadIdx.x & 63;
    int s = off[r];
    int e = off[r + 1];
    float a0 = 0.f, a1 = 0.f, a2 = 0.f, a3 = 0.f;
    float a4 = 0.f, a5 = 0.f, a6 = 0.f, a7 = 0.f;
    int i = s;
    for (; i + 8 <= e; i += 8) {
        int2 e0 = csr[i];     int2 e1 = csr[i + 1];
        int2 e2 = csr[i + 2]; int2 e3 = csr[i + 3];
        int2 e4 = csr[i + 4]; int2 e5 = csr[i + 5];
        int2 e6 = csr[i + 6]; int2 e7 = csr[i + 7];
        float y0 = bf2f(Yb[(size_t)e0.x * F_IN + lane]);
        float y1 = bf2f(Yb[(size_t)e1.x * F_IN + lane]);
        float y2 = bf2f(Yb[(size_t)e2.x * F_IN + lane]);
        float y3 = bf2f(Yb[(size_t)e3.x * F_IN + lane]);
        float y4 = bf2f(Yb[(size_t)e4.x * F_IN + lane]);
        float y5 = bf2f(Yb[(size_t)e5.x * F_IN + lane]);
        float y6 = bf2f(Yb[(size_t)e6.x * F_IN + lane]);
        float y7 = bf2f(Yb[(size_t)e7.x * F_IN + lane]);
        a0 = fmaf(__int_as_float(e0.y), y0, a0);
        a1 = fmaf(__int_as_float(e1.y), y1, a1);
        a2 = fmaf(__int_as_float(e2.y), y2, a2);
        a3 = fmaf(__int_as_float(e3.y), y3, a3);
        a4 = fmaf(__int_as_float(e4.y), y4, a4);
        a5 = fmaf(__int_as_float(e5.y), y5, a5);
        a6 = fmaf(__int_as_float(e6.y), y6, a6);
        a7 = fmaf(__int_as_float(e7.y), y7, a7);
    }
    for (; i + 4 <= e; i += 4) {
        int2 e0 = csr[i];     int2 e1 = csr[i + 1];
        int2 e2 = csr[i + 2]; int2 e3 = csr[i + 3];
        a0 = fmaf(__int_as_float(e0.y), bf2f(Yb[(size_t)e0.x * F_IN + lane]), a0);
        a1 = fmaf(__int_as_float(e1.y), bf2f(Yb[(size_t)e1.x * F_IN + lane]), a1);
        a2 = fmaf(__int_as_float(e2.y), bf2f(Yb[(size_t)e2.x * F_IN + lane]), a2);
        a3 = fmaf(__int_as_float(e3.y), bf2f(Yb[(size_t)e3.x * F_IN + lane]), a3);
    }
    for (; i < e; ++i) {
        int2 ed = csr[i];
        a0 = fmaf(__int_as_float(ed.y), bf2f(Yb[(size_t)ed.x * F_IN + lane]), a0);
    }
    float acc = ((a0 + a1) + (a2 + a3)) + ((a4 + a5) + (a6 + a7));
    size_t o = (size_t)r * F_IN + lane;
    outb[o] = f2bf(2.f * acc - X[o]);
}

// ---------------- MFMA GEMM: out = [Xb|T1b|T2b] @ W + b ---------------------
__global__ __launch_bounds__(512) void gemm_mfma(
    const unsigned short* __restrict__ Xb, const unsigned short* __restrict__ T1b,
    const unsigned short* __restrict__ T2b, const unsigned short* __restrict__ Wp,
    const float* __restrict__ bias, float* __restrict__ out)
{
    __shared__ __align__(16) unsigned short Wl[24576];  // 48 KB
    int t = threadIdx.x;
    for (int i = t; i < 3072; i += 512)
        ((float4*)Wl)[i] = ((const float4*)Wp)[i];
    __syncthreads();

    int w   = t >> 6;
    int l   = t & 63;
    int c15 = l & 15;
    int g   = l >> 4;
    int brow = blockIdx.x * 128 + w * 16;
    int arow = brow + c15;

    const unsigned short* srcs[3] = {Xb, T1b, T2b};
    bf16x8 a[6];
    #pragma unroll
    for (int kk = 0; kk < 6; ++kk) {
        const unsigned short* src = srcs[kk >> 1];
        a[kk] = *(const bf16x8*)(src + (size_t)arow * F_IN + (kk & 1) * 32 + g * 8);
    }

    f32x4 acc[8];
    #pragma unroll
    for (int n = 0; n < 8; ++n) acc[n] = (f32x4){0.f, 0.f, 0.f, 0.f};

    int gx = g ^ (c15 & 3);
    #pragma unroll
    for (int kk = 0; kk < 6; ++kk) {
        #pragma unroll
        for (int n = 0; n < 8; ++n) {
            int idx = (((kk * 8 + n) * 16 + c15) * 4 + gx) * 8;
            bf16x8 b = *(const bf16x8*)&Wl[idx];
            acc[n] = __builtin_amdgcn_mfma_f32_16x16x32_bf16(a[kk], b, acc[n], 0, 0, 0);
        }
    }

    #pragma unroll
    for (int n = 0; n < 8; ++n) {
        float bv = bias[n * 16 + c15];
        #pragma unroll
        for (int r = 0; r < 4; ++r) {
            int orow = brow + g * 4 + r;
            out[(size_t)orow * F_OUT + n * 16 + c15] = acc[n][r] + bv;
        }
    }
}

extern "C" void kernel_launch(void* const* d_in, const int* in_sizes, int n_in,
                              void* d_out, int out_size, void* d_ws, size_t ws_size,
                              hipStream_t stream)
{
    const float* X    = (const float*)d_in[0];
    const int*   erow = (const int*)  d_in[1];
    const int*   ecol = (const int*)  d_in[2];
    const float* eval = (const float*)d_in[3];
    const float* W    = (const float*)d_in[4];
    const float* bias = (const float*)d_in[5];
    float* out = (float*)d_out;

    // ws layout: Xb (8MB) + T1b (8MB) + T2b (8MB) + Wp (48KB) < 32MB
    unsigned short* Xb  = (unsigned short*)d_ws;
    unsigned short* T1b = Xb  + (size_t)N_NODES * F_IN;
    unsigned short* T2b = T1b + (size_t)N_NODES * F_IN;
    unsigned short* Wp  = T2b + (size_t)N_NODES * F_IN;

    // CSR scratch in d_out (~17 MB < 33.5 MB); all dead before gemm writes out.
    int*  off  = (int*)d_out;                 // 65537 (pad 65600)
    int2* csr  = (int2*)(off + 65600);        // 1M x 8 B
    int*  boff = (int*)(csr + N_EDGES);       // 1025 (pad 1088)
    int*  bcur = boff + 1088;                 // 1024
    int2* bent = (int2*)(bcur + 1024);        // 1M x 8 B

    wpack<<<96, 256, 0, stream>>>(W, Wp);
    xconvert<<<N_NODES * F_IN / 4 / 256, 256, 0, stream>>>(X, Xb);

    zero_bcur<<<1, 256, 0, stream>>>(bcur);
    bucket_hist<<<128, 256, 0, stream>>>(erow, bcur);
    scan_buckets<<<1, 256, 0, stream>>>(bcur, boff);
    bucketize<<<128, 256, 0, stream>>>(erow, ecol, eval, bcur, bent);

    // fused: CSR window build + T1b = bf16(L @ Xb)
    build_spmm1<<<NB, 256, 0, stream>>>(boff, bent, off, csr, Xb, T1b);
    // T2b = bf16(2 L T1b - X)
    spmm2<<<N_NODES / 4, 256, 0, stream>>>(off, csr, T1b, X, T2b);

    // out = [Xb|T1b|T2b] @ W + b   (bf16 MFMA, f32 accumulate)
    gemm_mfma<<<N_NODES / 128, 512, 0, stream>>>(Xb, T1b, T2b, Wp, bias, out);
}